// Round 9
// baseline (464.322 us; speedup 1.0000x reference)
//
#include <hip/hip_runtime.h>

// LocalExpansion: out[b,h,(y,x),c,d] = in[b,h,(y+i-3,x+j-3),d], c = i*7+j,
// zero-filled outside the image. 462 MB output write, ~9.4 MB input.
//
// v9: decouple loads from stores. The harness fill kernel proves pure
// streaming stores hit 6.3 TB/s at ~3 waves/CU; our gather kernel ran at
// ~2.7 TB/s because every store's data hung off a fresh L1/L2 gather
// round-trip. Now: block = (bh, row, 24-px half-row). Phase 1 stages the
// 7-row x 30-px halo band into LDS (53,760 B, zero-filled borders).
// Phase 2 is a pure streaming-store loop (ds_read_b128 -> store, no
// bounds checks, no global loads) over the block's 301,056 contiguous
// output bytes — structurally the same as the fill kernel.
// LDS 53,760 B -> 3 blocks/CU -> 12 waves/CU. 1536 blocks = 6/CU exact.

#define KH 7
#define KW 7
#define PAD 3
#define HEIGHT 48
#define WIDTH 48
#define DDIM 64
#define NPIX (HEIGHT * WIDTH)       // 2304
#define KK (KH * KW)                // 49
#define HALF 24                     // output pixels per block (x direction)
#define LW (HALF + KW - 1)          // 30 staged pixels per row
#define STAGE4 (KH * LW * (DDIM/4))        // 3360 float4 = 53,760 B
#define OUT4 (HALF * KK * (DDIM/4))        // 18816 float4 per block

__global__ __launch_bounds__(256) void local_expansion_kernel(
    const float* __restrict__ in, float* __restrict__ out) {
    __shared__ float4 lds[STAGE4];

    int blk = blockIdx.x;
    int h   = blk & 1;              // which half-row
    int yb  = blk >> 1;
    int y0  = yb % HEIGHT;
    int bh  = yb / HEIGHT;
    int x0  = h * HALF;

    const float4* in4 = (const float4*)in;

    // Phase 1: stage 7 rows x 30 px x 64 f32 halo band, zero-filled OOB.
    for (int s = threadIdx.x; s < STAGE4; s += 256) {
        int r   = s / (LW * 16);        // staged row 0..6
        int rem = s - r * (LW * 16);
        int p   = rem >> 4;             // staged px 0..29
        int d4  = rem & 15;
        int gy  = y0 - PAD + r;
        int gx  = x0 - PAD + p;
        float4 v = make_float4(0.f, 0.f, 0.f, 0.f);
        if ((unsigned)gy < (unsigned)HEIGHT && (unsigned)gx < (unsigned)WIDTH)
            v = in4[(bh * NPIX + gy * WIDTH + gx) * 16 + d4];
        lds[s] = v;
    }
    __syncthreads();

    // Phase 2: pure streaming stores of 24 px x 49 c x 64 f32, contiguous.
    // source in LDS: row i, px (q + j); always in range (halo pre-staged).
    int obase = (bh * NPIX + y0 * WIDTH + x0) * (KK * 16);
    float4* o4 = (float4*)out + obase;
    for (int s = threadIdx.x; s < OUT4; s += 256) {
        int q   = s / (KK * 16);        // output px within block 0..23
        int rem = s - q * (KK * 16);
        int c   = rem >> 4;             // filter index 0..48
        int d4  = rem & 15;
        int i   = c / KW;
        int j   = c - i * KW;
        o4[s] = lds[(i * LW + q + j) * 16 + d4];
    }
}

extern "C" void kernel_launch(void* const* d_in, const int* in_sizes, int n_in,
                              void* d_out, int out_size, void* d_ws, size_t ws_size,
                              hipStream_t stream) {
    const float* x = (const float*)d_in[0];
    float* out = (float*)d_out;

    // 16 bh-slices x 48 rows x 2 half-rows = 1536 blocks; covers all of
    // out_size = 115,605,504 floats exactly.
    int blocks = 16 * HEIGHT * 2;
    local_expansion_kernel<<<dim3(blocks), 256, 0, stream>>>(x, out);
}